// Round 9
// baseline (257.669 us; speedup 1.0000x reference)
//
#include <hip/hip_runtime.h>

// Problem constants (from reference setup_inputs)
constexpr int B   = 8;
constexpr int C   = 256;
constexpr int HW  = 128 * 128;    // 16384 pixels per plane
constexpr int HW4 = HW / 4;       // 4096 float4 per plane
constexpr int K   = 64;           // selected channels
constexpr int U   = C - K;        // 192 unselected channels

// Native 4-float vector for __builtin_nontemporal_store (HIP float4 is a class).
typedef float nfloat4 __attribute__((ext_vector_type(4)));

// Ranking-equivalent uncertainty (rank-invariant transform of -s*log(s+eps)):
//   u' = log2(1+e^-v) * rcp(1+e^-v)
__device__ __forceinline__ float uncert_rank(float v) {
    float t = __expf(-v);
    float a = 1.0f + t;
    return __log2f(a) * __builtin_amdgcn_rcpf(a);
}

// Kernel 1: score[b,c] = rank-equivalent mean uncertainty over the plane.
// One block (256 threads) per (b,c) plane. BW-bound (~21 us for 134 MB).
__global__ __launch_bounds__(256) void score_kernel(const float* __restrict__ x,
                                                    float* __restrict__ score) {
    const int plane = blockIdx.x;                       // b*C + c
    const float4* xp = (const float4*)(x + (size_t)plane * HW);
    const int t = threadIdx.x;

    float acc = 0.0f;
#pragma unroll
    for (int i = 0; i < 16; ++i) {
        float4 v = xp[t + i * 256];
        acc += uncert_rank(v.x) + uncert_rank(v.y) + uncert_rank(v.z) + uncert_rank(v.w);
    }
#pragma unroll
    for (int off = 32; off > 0; off >>= 1) acc += __shfl_down(acc, off, 64);

    __shared__ float smem[4];
    if ((t & 63) == 0) smem[t >> 6] = acc;
    __syncthreads();
    if (t == 0) score[plane] = smem[0] + smem[1] + smem[2] + smem[3];  // scale rank-invariant
}

// Kernel 2 (fused topk + attn + multiply) — 4-thread cooperative columns:
// every memory access is 16 B/lane (dwordx4), occupancy and traffic unchanged
// vs the scalar version (512 blocks = 2/CU, 8 waves/CU; 1x read x + 1x write out).
//
// Block = 4 waves, 64 float4-columns (256 px). Thread (sub = t>>6, col = t&63):
//  - Phase A: wave `sub` loads selected-channel ranks [16*sub, 16*sub+16) for
//    all 64 columns — 1 KB/instruction coalesced — stashing 16 float4 (64 VGPR)
//    while accumulating a partial weighted sum.
//  - LDS reduce (4 partials/column) -> attn4[col] = sigmoid(bias + total).
//  - Phase A': wave `sub` writes its 16 stashed channels (NT, no re-read).
//  - Phase B: wave `sub` streams 48 of the 192 unselected channels (NT).
__global__ __launch_bounds__(256, 2) void attn_mul_kernel(const float* __restrict__ x,
                                                          const float* __restrict__ score,
                                                          const float* __restrict__ w,
                                                          const float* __restrict__ bias,
                                                          float* __restrict__ out) {
    const int b     = blockIdx.x >> 6;                  // 64 blocks per batch
    const int chunk = blockIdx.x & 63;                  // 64 float4-columns each
    const int t     = threadIdx.x;                      // also = channel for ranking
    const int sub   = t >> 6;                           // wave index 0..3
    const int col   = t & 63;                           // column within chunk

    __shared__ float sc[C];
    __shared__ float ws[K];
    __shared__ int   chs[K];                            // selected channel per rank
    __shared__ int   unch[U];                           // unselected channels
    __shared__ float4 part[4][64];                      // per-wave partial sums
    __shared__ float4 attnS[64];                        // final attention per column

    sc[t] = score[b * C + t];
    if (t < K) ws[t] = w[t];
    __syncthreads();

    {   // exact rank with lax.top_k tie-break (lower index first)
        const float my = sc[t];
        int rank = 0;
#pragma unroll 8
        for (int j = 0; j < C; ++j) {
            float o = sc[j];
            rank += (o < my) || (o == my && j < t);
        }
        if (rank < K) chs[rank] = t;
        else          unch[rank - K] = t;
    }
    __syncthreads();

    const int col4 = chunk * 64 + col;                  // float4 index in plane
    const float4* xb4 = (const float4*)(x + (size_t)b * C * HW);
    float*        obf = out + (size_t)b * C * HW;

    // Phase A: partial weighted sum over 16 selected ranks, stashing values
    // (fully unrolled -> static register indices, no scratch).
    float4 st[16];
    float ax = 0.f, ay = 0.f, az = 0.f, aw = 0.f;
#pragma unroll
    for (int j = 0; j < 16; ++j) {
        const int k = sub * 16 + j;                     // wave-uniform rank index
        float4 v = xb4[(size_t)chs[k] * HW4 + col4];
        st[j] = v;
        const float wk = ws[k];
        ax += wk * v.x; ay += wk * v.y; az += wk * v.z; aw += wk * v.w;
    }
    { float4 p; p.x = ax; p.y = ay; p.z = az; p.w = aw; part[sub][col] = p; }
    __syncthreads();

    if (t < 64) {                                       // wave 0 finishes the sums
        float4 p0 = part[0][t], p1 = part[1][t], p2 = part[2][t], p3 = part[3][t];
        const float b0 = bias[0];
        float4 a4;
        a4.x = __builtin_amdgcn_rcpf(1.0f + __expf(-(p0.x + p1.x + p2.x + p3.x + b0)));
        a4.y = __builtin_amdgcn_rcpf(1.0f + __expf(-(p0.y + p1.y + p2.y + p3.y + b0)));
        a4.z = __builtin_amdgcn_rcpf(1.0f + __expf(-(p0.z + p1.z + p2.z + p3.z + b0)));
        a4.w = __builtin_amdgcn_rcpf(1.0f + __expf(-(p0.w + p1.w + p2.w + p3.w + b0)));
        attnS[t] = a4;
    }
    __syncthreads();
    const float4 a4 = attnS[col];

    // Phase A': this wave's 16 selected channels from the stash (NT dwordx4).
#pragma unroll
    for (int j = 0; j < 16; ++j) {
        const int k = sub * 16 + j;
        nfloat4 o = {st[j].x * a4.x, st[j].y * a4.y, st[j].z * a4.z, st[j].w * a4.w};
        __builtin_nontemporal_store(o,
            (nfloat4*)(obf + ((size_t)chs[k] * HW4 + col4) * 4));
    }

    // Phase B: this wave streams 48 unselected channels (NT dwordx4).
#pragma unroll 8
    for (int j = 0; j < U / 4; ++j) {
        const int ch = unch[sub * (U / 4) + j];         // wave-uniform channel
        const size_t idx = (size_t)ch * HW4 + col4;
        float4 v = xb4[idx];
        nfloat4 o = {v.x * a4.x, v.y * a4.y, v.z * a4.z, v.w * a4.w};
        __builtin_nontemporal_store(o, (nfloat4*)(obf + idx * 4));
    }
}

extern "C" void kernel_launch(void* const* d_in, const int* in_sizes, int n_in,
                              void* d_out, int out_size, void* d_ws, size_t ws_size,
                              hipStream_t stream) {
    const float* x    = (const float*)d_in[0];
    const float* w    = (const float*)d_in[1];
    const float* bias = (const float*)d_in[2];
    float* out = (float*)d_out;

    float* score = (float*)d_ws;               // 2048 floats = 8 KiB

    score_kernel<<<B * C, 256, 0, stream>>>(x, score);
    attn_mul_kernel<<<B * 64, 256, 0, stream>>>(x, score, w, bias, out);
}